// Round 2
// 683.442 us; speedup vs baseline: 1.0315x; 1.0315x over previous
//
#include <hip/hip_runtime.h>
#include <math.h>

#define S_ 256
#define B_ 16
#define D_ 512
#define V_ 32000
#define L_ 4
#define DEC_ 0.6065306597126334f   // float(exp(-1/2))

typedef short v8s __attribute__((ext_vector_type(8)));
typedef float v4f __attribute__((ext_vector_type(4)));

static __device__ __forceinline__ short f2bf(float f){
  union { float f; unsigned u; } v; v.f = f;
  unsigned r = (v.u + 0x7FFFu + ((v.u >> 16) & 1u)) >> 16;  // RNE
  return (short)(unsigned short)r;
}

// ---------------- encoder GEMM + scratch zero-init ----------------
// X[s*B+b][n] = emb[ids[b][s]] . enc_W[n][:] + enc_b[n]
__global__ __launch_bounds__(256) void k_gemm_enc(const int* __restrict__ ids,
                                                  const float* __restrict__ emb,
                                                  const float* __restrict__ encW,
                                                  const float* __restrict__ encb,
                                                  float* __restrict__ X,
                                                  unsigned* __restrict__ counts,
                                                  unsigned* __restrict__ bunz,
                                                  float* __restrict__ accum){
  __shared__ __align__(16) short As[64*40];
  __shared__ __align__(16) short Bs[64*40];
  __shared__ int ids_s[64];
  const int t = threadIdx.x;
  const int bm = blockIdx.x, bn = blockIdx.y;
  // zero-init scratch (later kernels run after this kernel completes)
  if (bn == 0 && bm < 16){
    int g = bm*256 + t;
    counts[g] = 0u;
    bunz[g] = 0u;
    if (g < 2) accum[g] = 0.0f;
  }
  if (t < 64){
    int mg = bm*64 + t;
    int s = mg >> 4, b = mg & 15;       // row r = s*B + b
    ids_s[t] = ids[b * S_ + s];
  }
  __syncthreads();
  const int arow = t >> 2;
  const int kc = (t & 3) * 8;
  const int wave = t >> 6;
  const int l = t & 63;
  const int lm = l & 15;
  const int q = l >> 4;
  v4f acc[4] = {};
  for (int k0 = 0; k0 < D_; k0 += 32){
    const float* asrc = emb + (size_t)ids_s[arow] * D_ + k0 + kc;
    float4 a0 = *(const float4*)asrc;
    float4 a1 = *(const float4*)(asrc + 4);
    const float* bsrc = encW + (size_t)(bn*64 + arow) * D_ + k0 + kc;
    float4 b0 = *(const float4*)bsrc;
    float4 b1 = *(const float4*)(bsrc + 4);
    v8s av, bv;
    av[0]=f2bf(a0.x); av[1]=f2bf(a0.y); av[2]=f2bf(a0.z); av[3]=f2bf(a0.w);
    av[4]=f2bf(a1.x); av[5]=f2bf(a1.y); av[6]=f2bf(a1.z); av[7]=f2bf(a1.w);
    bv[0]=f2bf(b0.x); bv[1]=f2bf(b0.y); bv[2]=f2bf(b0.z); bv[3]=f2bf(b0.w);
    bv[4]=f2bf(b1.x); bv[5]=f2bf(b1.y); bv[6]=f2bf(b1.z); bv[7]=f2bf(b1.w);
    *(v8s*)&As[arow*40 + kc] = av;
    *(v8s*)&Bs[arow*40 + kc] = bv;
    __syncthreads();
    v8s af = *(const v8s*)&As[(wave*16 + lm)*40 + q*8];
    #pragma unroll
    for (int n = 0; n < 4; ++n){
      v8s bf = *(const v8s*)&Bs[(n*16 + lm)*40 + q*8];
      acc[n] = __builtin_amdgcn_mfma_f32_16x16x32_bf16(af, bf, acc[n], 0, 0, 0);
    }
    __syncthreads();
  }
  // C/D layout: col = lane&15, row = (lane>>4)*4 + reg  [m89/m91 verified]
  #pragma unroll
  for (int n = 0; n < 4; ++n){
    #pragma unroll
    for (int i = 0; i < 4; ++i){
      int mloc = wave*16 + q*4 + i;
      int nloc = n*16 + lm;
      int r  = bm*64 + mloc;
      int nn = bn*64 + nloc;
      X[(size_t)r * D_ + nn] = acc[n][i] + encb[nn];
    }
  }
}

// ---------------- encoder LIF scan (blocks 0..127) + cvec compute (blocks 128..159) ----------------
// cvec: c_j = err_b[j] @ inf_W[j]^T + inf_b[j]  (constant per launch; used by sim top-down)
__global__ __launch_bounds__(64) void k_scan(const float* __restrict__ X,
                                             unsigned char* __restrict__ bu,
                                             unsigned* __restrict__ bunz,
                                             const float* __restrict__ inf_W,
                                             const float* __restrict__ inf_b,
                                             const float* __restrict__ err_b,
                                             float* __restrict__ cvec){
  int bx = blockIdx.x;
  if (bx >= 128){
    int r = bx - 128;                       // 0..31
    int j = r >> 3;
    int dp = (r & 7) * 64 + threadIdx.x;    // 0..511
    const float* row = inf_W + ((size_t)j * D_ + dp) * D_;
    const float* eb = err_b + j * D_;
    float acc = inf_b[j * D_ + dp];
    for (int d = 0; d < D_; d += 8){
      float4 w0 = *(const float4*)(row + d);
      float4 w1 = *(const float4*)(row + d + 4);
      float4 e0 = *(const float4*)(eb + d);
      float4 e1 = *(const float4*)(eb + d + 4);
      acc += e0.x*w0.x + e0.y*w0.y + e0.z*w0.z + e0.w*w0.w;
      acc += e1.x*w1.x + e1.y*w1.y + e1.z*w1.z + e1.w*w1.w;
    }
    cvec[j * D_ + dp] = acc;
    return;
  }
  int g = bx * 64 + threadIdx.x;   // g = b*512 + d, 0..8191
  int b = g >> 9;
  float mem = 0.0f;
  for (int s0 = 0; s0 < S_; s0 += 8){
    float x[8];
    #pragma unroll
    for (int i = 0; i < 8; ++i) x[i] = X[(size_t)(s0 + i) * (B_*D_) + g];
    #pragma unroll
    for (int i = 0; i < 8; ++i){
      mem = mem * DEC_ + x[i];
      float sp = (mem >= 1.0f) ? 1.0f : 0.0f;   // atan_spike(mem - 1) == (mem >= 1)
      mem *= (1.0f - sp);
      bu[(size_t)(s0 + i) * (B_*D_) + g] = (unsigned char)sp;
      if (sp != 0.0f) atomicOr(&bunz[(s0 + i) * B_ + b], 1u);
    }
  }
}

// ---------------- helpers for the sim ----------------
__device__ __forceinline__ float wave_sum(float x){
  #pragma unroll
  for (int o = 32; o > 0; o >>= 1) x += __shfl_xor(x, o);
  return x;
}

__device__ void wave_matvec(const float* __restrict__ W, const float* __restrict__ bias,
                            const float x[8], float y[8], float* xs, int l){
  __syncthreads();
  #pragma unroll
  for (int i = 0; i < 8; ++i) xs[l + 64*i] = x[i];
  __syncthreads();
  #pragma unroll
  for (int i = 0; i < 8; ++i){
    int dp = l + 64*i;
    const float* row = W + (size_t)dp * D_;
    float acc = bias[dp];
    for (int d = 0; d < D_; d += 4){
      float4 w = *(const float4*)(row + d);
      acc += xs[d]*w.x + xs[d+1]*w.y + xs[d+2]*w.z + xs[d+3]*w.w;
    }
    y[i] = acc;
  }
}

__device__ void wave_ln(const float e[8], const float* __restrict__ g,
                        const float* __restrict__ bb, float out[8], int l){
  float s = 0.f;
  #pragma unroll
  for (int i = 0; i < 8; ++i) s += e[i];
  float m = wave_sum(s) * (1.0f/512.0f);
  float s2 = 0.f;
  #pragma unroll
  for (int i = 0; i < 8; ++i){ float d = e[i] - m; s2 += d*d; }
  float var = wave_sum(s2) * (1.0f/512.0f);
  float inv = 1.0f / sqrtf(var + 1e-5f);
  #pragma unroll
  for (int i = 0; i < 8; ++i){
    int d = l + 64*i;
    out[i] = (e[i] - m) * inv * g[d] + bb[d];
  }
}

// ---------------- fused: sim (blocks 0..15) + logits base stream (blocks 16..3215) ----------------
// The out_b broadcast has NO dependency on the sim, so it runs concurrently in the
// same kernel instead of serializing behind gemm->scan->sim. Regular (cached) stores:
// the only store path proven at 6.29 TB/s on this chip is regular dwordx4.
__global__ __launch_bounds__(64) void k_simstream(
    const float* __restrict__ gen_W, const float* __restrict__ gen_b,
    const float* __restrict__ inf_W, const float* __restrict__ inf_b,
    const float* __restrict__ err_g, const float* __restrict__ err_b,
    const float* __restrict__ st_g, const float* __restrict__ st_b,
    const unsigned char* __restrict__ bu8, const unsigned* __restrict__ bunz,
    const float* __restrict__ cvec,
    unsigned* __restrict__ counts, unsigned short* __restrict__ idxb,
    float* __restrict__ accum,
    const float* __restrict__ outb, float* __restrict__ out)
{
  __shared__ float xs[D_];
  __shared__ unsigned scnt;

  if (blockIdx.x >= 16){
    // ---- base stream: out[row][:] = out_b for every row; corrections applied by k_fix ----
    const int sbx = blockIdx.x - 16;
    const int chunk = sbx % 25;
    const int rg = sbx / 25;
    const int lane = threadIdx.x;
    const int colbase = chunk * 1280;
    v4f pay[5];
    #pragma unroll
    for (int k = 0; k < 5; ++k)
      pay[k] = *(const v4f*)(outb + colbase + k*256 + lane*4);
    for (int r = 0; r < 32; ++r){
      float* dst = out + (size_t)(rg*32 + r) * V_ + colbase;
      #pragma unroll
      for (int k = 0; k < 5; ++k)
        *(v4f*)(dst + k*256 + lane*4) = pay[k];
    }
    return;
  }

  // ---- main recurrent sim: one wave per batch ----
  const int b = blockIdx.x, l = threadIdx.x;
  float st[4][8], gm[4][8], im[4][8];
  #pragma unroll
  for (int j = 0; j < 4; ++j)
    #pragma unroll
    for (int i = 0; i < 8; ++i){ st[j][i]=0.f; gm[j][i]=0.f; im[j][i]=0.f; }

  bool okz = true;
  #pragma unroll
  for (int j = 0; j < 4; ++j)
    #pragma unroll
    for (int i = 0; i < 8; ++i){
      int d = j*512 + l + 64*i;
      okz = okz && (gen_b[d]==0.f) && (inf_b[d]==0.f) && (err_b[d]==0.f) && (st_b[d]==0.f);
    }
  const bool bias_zero = (__all((int)okz) != 0);

  unsigned long long fl[4];
  #pragma unroll
  for (int w = 0; w < 4; ++w){
    unsigned v = bunz[(w*64 + l) * B_ + b];
    fl[w] = __ballot(v != 0u);
  }

  bool state_zero = true;
  float spk_acc = 0.f, memp_acc = 0.f;

  for (int t = 0; t < S_; ++t){
    bool nz = ((fl[t >> 6] >> (t & 63)) & 1ull) != 0ull;
    if (state_zero && bias_zero && !nz) continue;   // zero fixed point: step is identity, td_t = 0
    state_zero = false;

    float bu[8];
    #pragma unroll
    for (int i = 0; i < 8; ++i) bu[i] = (float)bu8[(size_t)(t*B_ + b)*D_ + l + 64*i];

    // ---- bottom-up ----
    #pragma unroll
    for (int j = 0; j < 4; ++j){
      float y[8];
      wave_matvec(gen_W + (size_t)j*D_*D_, gen_b + j*D_, st[j], y, xs, l);
      float pred[8];
      #pragma unroll
      for (int i = 0; i < 8; ++i){
        gm[j][i] = gm[j][i]*DEC_ + y[i];
        pred[i] = (gm[j][i] >= 1.0f) ? 1.0f : 0.0f;
        gm[j][i] *= (1.0f - pred[i]);
      }
      float e[8];
      #pragma unroll
      for (int i = 0; i < 8; ++i){ float v = bu[i] - pred[i]; e[i] = v > 0.f ? v : 0.f; }
      float eo[8];
      wave_ln(e, err_g + j*D_, err_b + j*D_, eo, l);
      #pragma unroll
      for (int i = 0; i < 8; ++i) spk_acc += eo[i];
      float y2[8];
      wave_matvec(inf_W + (size_t)j*D_*D_, inf_b + j*D_, eo, y2, xs, l);
      float su[8];
      #pragma unroll
      for (int i = 0; i < 8; ++i){
        im[j][i] = im[j][i]*DEC_ + y2[i];
        su[i] = (im[j][i] >= 1.0f) ? 1.0f : 0.0f;
        im[j][i] *= (1.0f - su[i]);
        memp_acc += fabsf(im[j][i]);
      }
      float tmp[8];
      #pragma unroll
      for (int i = 0; i < 8; ++i) tmp[i] = st[j][i] + su[i];
      wave_ln(tmp, st_g + j*D_, st_b + j*D_, st[j], l);
      #pragma unroll
      for (int i = 0; i < 8; ++i) bu[i] = st[j][i] > 0.f ? st[j][i] : 0.f;
    }

    // ---- top-down (err == LN(0) == err_b identically, so inf input is cvec[j]) ----
    float td[8];
    #pragma unroll
    for (int i = 0; i < 8; ++i) td[i] = st[3][i];
    #pragma unroll
    for (int j = 3; j >= 0; --j){
      float y[8];
      wave_matvec(gen_W + (size_t)j*D_*D_, gen_b + j*D_, td, y, xs, l);
      #pragma unroll
      for (int i = 0; i < 8; ++i){
        gm[j][i] = gm[j][i]*DEC_ + y[i];
        float p = (gm[j][i] >= 1.0f) ? 1.0f : 0.0f;
        gm[j][i] *= (1.0f - p);
        td[i] = p;
      }
      #pragma unroll
      for (int i = 0; i < 8; ++i){
        float c = cvec[j*D_ + l + 64*i];
        im[j][i] = im[j][i]*DEC_ + c;
        float ss = (im[j][i] >= 1.0f) ? 1.0f : 0.0f;
        im[j][i] *= (1.0f - ss);
      }
    }

    if (l == 0) scnt = 0u;
    __syncthreads();
    unsigned base = (unsigned)(t*B_ + b) * D_;
    #pragma unroll
    for (int i = 0; i < 8; ++i){
      if (td[i] != 0.f){
        unsigned pos = atomicAdd(&scnt, 1u);
        idxb[base + pos] = (unsigned short)(l + 64*i);
      }
    }
    __syncthreads();
    if (l == 0) counts[t*B_ + b] = scnt;
  }
  spk_acc = wave_sum(spk_acc);
  memp_acc = wave_sum(memp_acc);
  if (l == 0){
    atomicAdd(&accum[0], spk_acc);
    atomicAdd(&accum[1], memp_acc);
  }
}

// ---------------- fix-up: scalar outputs + out_W column-gather corrections ----------------
// 128 blocks x 32 rows each. For this input all counts are 0 -> near-instant exit.
__global__ __launch_bounds__(64) void k_fix(const unsigned* __restrict__ counts,
                                            const unsigned short* __restrict__ idxb,
                                            const float* __restrict__ outW,
                                            const float* __restrict__ accum,
                                            float* __restrict__ out){
  const int lane = threadIdx.x;
  const int rg = blockIdx.x;
  if (rg == 0 && lane == 0){
    const float inv = 1.0f / (float)(B_ * D_ * S_);   // mean over (B,D), then /S
    out[(size_t)B_ * S_ * V_ + 0] = accum[0] * inv;
    out[(size_t)B_ * S_ * V_ + 1] = accum[1] * inv;
  }
  int prow = rg*32 + (lane & 31);                     // row = b*S + s (output order)
  unsigned myc = counts[(prow & 255) * B_ + (prow >> 8)];
  if (__ballot(myc != 0u) == 0ull) return;
  for (int r = 0; r < 32; ++r){
    unsigned cnt = (unsigned)__shfl((int)myc, r);
    if (cnt == 0u) continue;
    int row = rg*32 + r;
    int s = row & 255, b = row >> 8;
    unsigned base = (unsigned)(s * B_ + b) * D_;
    float* dst = out + (size_t)row * V_;
    for (int c = 0; c < 125; ++c){
      int off = c*256 + lane*4;
      v4f a = *(v4f*)(dst + off);
      for (unsigned i = 0; i < cnt; ++i){
        int d = idxb[base + i];
        a.x += outW[(size_t)(off+0)*D_ + d];
        a.y += outW[(size_t)(off+1)*D_ + d];
        a.z += outW[(size_t)(off+2)*D_ + d];
        a.w += outW[(size_t)(off+3)*D_ + d];
      }
      *(v4f*)(dst + off) = a;
    }
  }
}

extern "C" void kernel_launch(void* const* d_in, const int* in_sizes, int n_in,
                              void* d_out, int out_size, void* d_ws, size_t ws_size,
                              hipStream_t stream){
  (void)in_sizes; (void)n_in; (void)out_size; (void)ws_size;
  const int*   input_ids = (const int*)d_in[0];
  const float* embedding = (const float*)d_in[1];
  const float* enc_W = (const float*)d_in[2];
  const float* enc_b = (const float*)d_in[3];
  const float* gen_W = (const float*)d_in[4];
  const float* gen_b = (const float*)d_in[5];
  const float* inf_W = (const float*)d_in[6];
  const float* inf_b = (const float*)d_in[7];
  const float* err_g = (const float*)d_in[8];
  const float* err_b = (const float*)d_in[9];
  const float* st_g  = (const float*)d_in[10];
  const float* st_b  = (const float*)d_in[11];
  const float* out_W = (const float*)d_in[12];
  const float* out_b = (const float*)d_in[13];
  float* out = (float*)d_out;
  char* ws = (char*)d_ws;

  float*          X      = (float*)(ws + 0);                 // 4096*512*4 = 8388608
  unsigned char*  bu     = (unsigned char*)(ws + 8388608);   // 4096*512   = 2097152
  unsigned short* idxb   = (unsigned short*)(ws + 10485760); // 4096*512*2 = 4194304
  unsigned*       counts = (unsigned*)(ws + 14680064);       // 4096*4
  unsigned*       bunz   = (unsigned*)(ws + 14696448);       // 4096*4
  float*          cvec   = (float*)(ws + 14712832);          // 4*512*4
  float*          accum  = (float*)(ws + 14721024);          // 2*4

  hipLaunchKernelGGL(k_gemm_enc, dim3(64, 8), dim3(256), 0, stream,
                     input_ids, embedding, enc_W, enc_b, X, counts, bunz, accum);
  hipLaunchKernelGGL(k_scan, dim3(160), dim3(64), 0, stream,
                     X, bu, bunz, inf_W, inf_b, err_b, cvec);
  hipLaunchKernelGGL(k_simstream, dim3(16 + 3200), dim3(64), 0, stream,
                     gen_W, gen_b, inf_W, inf_b, err_g, err_b, st_g, st_b,
                     bu, bunz, cvec, counts, idxb, accum, out_b, out);
  hipLaunchKernelGGL(k_fix, dim3(128), dim3(64), 0, stream,
                     counts, idxb, out_W, accum, out);
}